// Round 1
// baseline (105.794 us; speedup 1.0000x reference)
//
#include <hip/hip_runtime.h>
#include <math.h>

// Problem constants (match reference)
#define BB   16      // batch
#define HH   16      // heads
#define DD   128     // head dim
#define BLK  16      // tokens per cache block
#define BPS  128     // blocks per sequence
#define SS   2048    // max context (BPS*BLK)
#define SCALE_F 0.08838834764831845f

#define NTHREADS 1024
#define NWAVES   16          // NTHREADS/64
#define TPW      (SS/NWAVES) // tokens per wave = 128

__global__ __launch_bounds__(NTHREADS, 1)
void paged_decode(const float* __restrict__ q,
                  const float* __restrict__ knew,
                  const float* __restrict__ vnew,
                  const float* __restrict__ kc,
                  const float* __restrict__ vc,
                  const int*   __restrict__ bt,
                  const int*   __restrict__ smap_g,
                  const int*   __restrict__ clen,
                  float*       __restrict__ out)
{
    __shared__ float sc[SS];             // scores -> probabilities (8 KB)
    __shared__ int   rb[SS];             // per-token row base, or -(j+1) if new-token j (8 KB)
    __shared__ float part[NWAVES][DD];   // per-wave PV partials (8 KB)
    __shared__ int   smap[BB];
    __shared__ float red[NWAVES];
    __shared__ float bmax, bsum;

    const int bid  = blockIdx.x;
    const int b    = bid >> 4;   // / HH
    const int h    = bid & 15;   // % HH
    const int t    = threadIdx.x;
    const int lane = t & 63;
    const int wave = t >> 6;
    const int len  = clen[b];

    if (t < BB) smap[t] = smap_g[t];
    __syncthreads();

    // ---- phase 0: per-token row base into LDS; detect new-token substitution ----
    for (int s = t; s < SS; s += NTHREADS) {
        int pb   = bt[b * BPS + (s >> 4)];
        int slot = pb * BLK + (s & 15);
        int enc  = (slot * HH + h) * DD;
        #pragma unroll
        for (int j = 0; j < BB; ++j)
            if (slot == smap[j]) enc = -(j + 1);
        rb[s] = enc;
    }
    __syncthreads();

    // wave lane mapping: 2 tokens per wave-iteration, 32 lanes x float4 per token
    const int half = lane >> 5;   // which token of the pair
    const int d4   = lane & 31;   // 4-dim group within D=128
    const float4 q4 = *(const float4*)(q + (b * HH + h) * DD + d4 * 4);
    const int s0 = wave * TPW;

    // ---- phase 1: scores = (q . k) * scale ----
    #pragma unroll 4
    for (int i = 0; i < TPW / 2; ++i) {
        int s   = s0 + i * 2 + half;
        int enc = rb[s];
        const float* kp = (enc >= 0)
            ? (kc + enc + d4 * 4)
            : (knew + ((-enc - 1) * HH + h) * DD + d4 * 4);
        float4 kv = *(const float4*)kp;
        float dot = q4.x * kv.x + q4.y * kv.y + q4.z * kv.z + q4.w * kv.w;
        dot += __shfl_xor(dot, 1);
        dot += __shfl_xor(dot, 2);
        dot += __shfl_xor(dot, 4);
        dot += __shfl_xor(dot, 8);
        dot += __shfl_xor(dot, 16);
        if (d4 == 0) sc[s] = (s < len) ? dot * SCALE_F : -1e30f;
    }
    __syncthreads();

    // ---- phase 2: block-wide max ----
    float m = fmaxf(sc[t], sc[t + NTHREADS]);
    #pragma unroll
    for (int msk = 32; msk >= 1; msk >>= 1)
        m = fmaxf(m, __shfl_xor(m, msk));
    if (lane == 0) red[wave] = m;
    __syncthreads();
    if (wave == 0) {
        float v = (lane < NWAVES) ? red[lane] : -1e30f;
        #pragma unroll
        for (int msk = 8; msk >= 1; msk >>= 1)
            v = fmaxf(v, __shfl_xor(v, msk));
        if (lane == 0) bmax = v;
    }
    __syncthreads();

    // ---- phase 3: exp + block-wide sum ----
    const float M = bmax;
    float e0 = expf(sc[t] - M);
    float e1 = expf(sc[t + NTHREADS] - M);
    sc[t] = e0;
    sc[t + NTHREADS] = e1;
    float sum = e0 + e1;
    #pragma unroll
    for (int msk = 32; msk >= 1; msk >>= 1)
        sum += __shfl_xor(sum, msk);
    if (lane == 0) red[wave] = sum;
    __syncthreads();
    if (wave == 0) {
        float v = (lane < NWAVES) ? red[lane] : 0.f;
        #pragma unroll
        for (int msk = 8; msk >= 1; msk >>= 1)
            v += __shfl_xor(v, msk);
        if (lane == 0) bsum = v;
    }
    __syncthreads();

    // ---- phase 4: PV accumulation ----
    float4 acc = make_float4(0.f, 0.f, 0.f, 0.f);
    #pragma unroll 4
    for (int i = 0; i < TPW / 2; ++i) {
        int s   = s0 + i * 2 + half;
        float p = sc[s];
        int enc = rb[s];
        const float* vp = (enc >= 0)
            ? (vc + enc + d4 * 4)
            : (vnew + ((-enc - 1) * HH + h) * DD + d4 * 4);
        float4 vv = *(const float4*)vp;
        acc.x += p * vv.x;
        acc.y += p * vv.y;
        acc.z += p * vv.z;
        acc.w += p * vv.w;
    }
    // fold the two token-halves together
    acc.x += __shfl_xor(acc.x, 32);
    acc.y += __shfl_xor(acc.y, 32);
    acc.z += __shfl_xor(acc.z, 32);
    acc.w += __shfl_xor(acc.w, 32);
    if (lane < 32) *(float4*)&part[wave][d4 * 4] = acc;
    __syncthreads();

    // ---- phase 5: cross-wave reduce + normalize + store ----
    if (t < DD) {
        float o = 0.f;
        #pragma unroll
        for (int w = 0; w < NWAVES; ++w) o += part[w][t];
        out[(b * HH + h) * DD + t] = o / bsum;
    }
}

extern "C" void kernel_launch(void* const* d_in, const int* in_sizes, int n_in,
                              void* d_out, int out_size, void* d_ws, size_t ws_size,
                              hipStream_t stream)
{
    const float* q    = (const float*)d_in[0];
    const float* knew = (const float*)d_in[1];
    const float* vnew = (const float*)d_in[2];
    const float* kc   = (const float*)d_in[3];
    const float* vc   = (const float*)d_in[4];
    const int*   bt   = (const int*)d_in[5];
    const int*   smap = (const int*)d_in[6];
    const int*   clen = (const int*)d_in[7];
    float*       out  = (float*)d_out;

    paged_decode<<<dim3(BB * HH), dim3(NTHREADS), 0, stream>>>(
        q, knew, vnew, kc, vc, bt, smap, clen, out);
}

// Round 2
// 98.835 us; speedup vs baseline: 1.0704x; 1.0704x over previous
//
#include <hip/hip_runtime.h>
#include <math.h>

// Problem constants (match reference)
#define BB   16      // batch
#define HH   16      // heads
#define DD   128     // head dim
#define BLK  16      // tokens per cache block
#define BPS  128     // blocks per sequence
#define SS   2048    // max context (BPS*BLK)
#define SCALE_F 0.08838834764831845f

#define SPLIT 8
#define CHUNK (SS / SPLIT)    // 256 tokens per partial block
#define NT1   256             // threads per partial block
#define NW1   4               // waves per partial block
#define TPW1  (CHUNK / NW1)   // 64 tokens per wave

// ---------------- kernel 1: per-chunk partial attention ----------------
// grid: B*H*SPLIT blocks; block (b,h,c) handles tokens [c*CHUNK, (c+1)*CHUNK)
// writes: ml[bid] = (m, l), pacc[bid][128] = unnormalized PV accumulator
__global__ __launch_bounds__(NT1, 8)
void pd_partial(const float* __restrict__ q,
                const float* __restrict__ knew,
                const float* __restrict__ vnew,
                const float* __restrict__ kc,
                const float* __restrict__ vc,
                const int*   __restrict__ bt,
                const int*   __restrict__ smap_g,
                const int*   __restrict__ clen,
                float*       __restrict__ ml,
                float*       __restrict__ pacc)
{
    __shared__ float sc[CHUNK];          // scores -> probabilities (1 KB)
    __shared__ int   rb[CHUNK];          // row base or -(j+1) for new-token j (1 KB)
    __shared__ float part[NW1][DD];      // per-wave PV partials (2 KB)
    __shared__ int   smap[BB];
    __shared__ float redm[NW1], reds[NW1];

    const int bid  = blockIdx.x;
    const int c    = bid & (SPLIT - 1);
    const int bh   = bid >> 3;           // SPLIT == 8
    const int b    = bh >> 4;
    const int h    = bh & 15;
    const int t    = threadIdx.x;
    const int lane = t & 63;
    const int wave = t >> 6;
    const int len  = clen[b];
    const int sbase = c * CHUNK;

    if (t < BB) smap[t] = smap_g[t];
    __syncthreads();

    // per-token row base (256 tokens, 1 per thread)
    {
        int s    = sbase + t;
        int pb   = bt[b * BPS + (s >> 4)];
        int slot = pb * BLK + (s & 15);
        int enc  = (slot * HH + h) * DD;
        #pragma unroll
        for (int j = 0; j < BB; ++j)
            if (slot == smap[j]) enc = -(j + 1);
        rb[t] = enc;
    }
    __syncthreads();

    // wave lane mapping: 2 tokens per iteration, 32 lanes x float4 per token
    const int half = lane >> 5;
    const int d4   = lane & 31;
    const float4 q4 = *(const float4*)(q + bh * DD + d4 * 4);
    const int w0 = wave * TPW1;

    // ---- scores ----
    #pragma unroll 8
    for (int i = 0; i < TPW1 / 2; ++i) {
        int sl  = w0 + i * 2 + half;
        int s   = sbase + sl;
        int enc = rb[sl];
        const float* kp = (enc >= 0)
            ? (kc + enc + d4 * 4)
            : (knew + ((-enc - 1) * HH + h) * DD + d4 * 4);
        float4 kv = *(const float4*)kp;
        float dot = q4.x * kv.x + q4.y * kv.y + q4.z * kv.z + q4.w * kv.w;
        dot += __shfl_xor(dot, 1);
        dot += __shfl_xor(dot, 2);
        dot += __shfl_xor(dot, 4);
        dot += __shfl_xor(dot, 8);
        dot += __shfl_xor(dot, 16);
        if (d4 == 0) sc[sl] = (s < len) ? dot * SCALE_F : -1e30f;
    }
    __syncthreads();

    // ---- chunk max ----
    float m = sc[t];
    #pragma unroll
    for (int msk = 32; msk >= 1; msk >>= 1)
        m = fmaxf(m, __shfl_xor(m, msk));
    if (lane == 0) redm[wave] = m;
    __syncthreads();
    const float M = fmaxf(fmaxf(redm[0], redm[1]), fmaxf(redm[2], redm[3]));

    // ---- exp + chunk sum ----
    float e = expf(sc[t] - M);
    sc[t] = e;
    float ssum = e;
    #pragma unroll
    for (int msk = 32; msk >= 1; msk >>= 1)
        ssum += __shfl_xor(ssum, msk);
    if (lane == 0) reds[wave] = ssum;
    __syncthreads();   // publishes sc[] rewrites and reds[]

    // ---- PV accumulation ----
    float4 acc = make_float4(0.f, 0.f, 0.f, 0.f);
    #pragma unroll 8
    for (int i = 0; i < TPW1 / 2; ++i) {
        int sl  = w0 + i * 2 + half;
        float p = sc[sl];
        int enc = rb[sl];
        const float* vp = (enc >= 0)
            ? (vc + enc + d4 * 4)
            : (vnew + ((-enc - 1) * HH + h) * DD + d4 * 4);
        float4 vv = *(const float4*)vp;
        acc.x += p * vv.x;
        acc.y += p * vv.y;
        acc.z += p * vv.z;
        acc.w += p * vv.w;
    }
    acc.x += __shfl_xor(acc.x, 32);
    acc.y += __shfl_xor(acc.y, 32);
    acc.z += __shfl_xor(acc.z, 32);
    acc.w += __shfl_xor(acc.w, 32);
    if (lane < 32) *(float4*)&part[wave][d4 * 4] = acc;
    __syncthreads();

    if (t < DD) {
        float o = part[0][t] + part[1][t] + part[2][t] + part[3][t];
        pacc[bid * DD + t] = o;
    }
    if (t == 0) {
        float L = reds[0] + reds[1] + reds[2] + reds[3];
        ml[bid * 2]     = M;
        ml[bid * 2 + 1] = L;
    }
}

// ---------------- kernel 2: combine SPLIT partials per (b,h) ----------------
__global__ __launch_bounds__(DD)
void pd_combine(const float* __restrict__ ml,
                const float* __restrict__ pacc,
                float*       __restrict__ out)
{
    const int bh = blockIdx.x;
    const int t  = threadIdx.x;  // 0..127

    float m[SPLIT], l[SPLIT];
    float M = -1e30f;
    #pragma unroll
    for (int i = 0; i < SPLIT; ++i) {
        m[i] = ml[(bh * SPLIT + i) * 2];
        l[i] = ml[(bh * SPLIT + i) * 2 + 1];
        M = fmaxf(M, m[i]);
    }
    float denom = 0.f, o = 0.f;
    #pragma unroll
    for (int i = 0; i < SPLIT; ++i) {
        float w = expf(m[i] - M);
        denom += w * l[i];
        o     += w * pacc[(bh * SPLIT + i) * DD + t];
    }
    out[bh * DD + t] = o / denom;
}

extern "C" void kernel_launch(void* const* d_in, const int* in_sizes, int n_in,
                              void* d_out, int out_size, void* d_ws, size_t ws_size,
                              hipStream_t stream)
{
    const float* q    = (const float*)d_in[0];
    const float* knew = (const float*)d_in[1];
    const float* vnew = (const float*)d_in[2];
    const float* kc   = (const float*)d_in[3];
    const float* vc   = (const float*)d_in[4];
    const int*   bt   = (const int*)d_in[5];
    const int*   smap = (const int*)d_in[6];
    const int*   clen = (const int*)d_in[7];
    float*       out  = (float*)d_out;

    float* ml   = (float*)d_ws;                    // [B*H*SPLIT][2]
    float* pacc = (float*)d_ws + BB * HH * SPLIT * 2;  // [B*H*SPLIT][DD]

    pd_partial<<<dim3(BB * HH * SPLIT), dim3(NT1), 0, stream>>>(
        q, knew, vnew, kc, vc, bt, smap, clen, ml, pacc);
    pd_combine<<<dim3(BB * HH), dim3(DD), 0, stream>>>(ml, pacc, out);
}